// Round 11
// baseline (243.456 us; speedup 1.0000x reference)
//
#include <hip/hip_runtime.h>
#include <math.h>

#define N_NODES 100000
#define N_EDGES 1600000
#define IN_DIM 128
#define HID_DIM 64
#define OUT_DIM 40

#define NPAD 102400

#define BUCKET_SHIFT 7
#define BUCKET_NODES 128
#define N_BUCKETS 782          // ceil(100000/128)
#define CHUNK 4096
#define N_CHUNKS 392           // 8 XCD groups x 49; 392*4096 >= N_EDGES

typedef _Float16 f16;
typedef _Float16 f16x2 __attribute__((ext_vector_type(2)));
typedef _Float16 f16x4 __attribute__((ext_vector_type(4)));
typedef _Float16 f16x8 __attribute__((ext_vector_type(8)));
typedef float f32x4 __attribute__((ext_vector_type(4)));

// -------- workspace layout --------
// ints:  hist[N_CHUNKS*N_BUCKETS] | base[N_BUCKETS*N_CHUNKS] | bucketTotal[1024] |
//        bucketBase[1024] | row_start[NPAD] | cnt[NPAD] | csr[E] | stage[E]
// floats: dinv[NPAD]
// f16:    h1p[N*64] | h2p[N*40] | w1f[8192] | w2f[3072]
// NO memset needed: every buffer fully written before read each launch.

// 1) per-chunk LDS histogram over dst buckets; coalesced row write
__global__ __launch_bounds__(256) void hist_kernel(const int* __restrict__ dst,
                                                   int* __restrict__ hist) {
    __shared__ int lh[N_BUCKETS];
    int c = blockIdx.x;
    int t = threadIdx.x;
    for (int b = t; b < N_BUCKETS; b += 256) lh[b] = 0;
    __syncthreads();
    int e0 = c * CHUNK;
    for (int i = t; i < CHUNK; i += 256) {
        int e = e0 + i;
        if (e < N_EDGES) atomicAdd(&lh[dst[e] >> BUCKET_SHIFT], 1);
    }
    __syncthreads();
    for (int b = t; b < N_BUCKETS; b += 256) hist[c * N_BUCKETS + b] = lh[b];
}

// 2) per-bucket exclusive scan over chunks -> base[b][c], bucketTotal[b]
__global__ __launch_bounds__(256) void scan_chunks_kernel(const int* __restrict__ hist,
                                                          int* __restrict__ base,
                                                          int* __restrict__ bucketTotal) {
    __shared__ int lds[256];
    int b = blockIdx.x;
    int t = threadIdx.x;
    int v[2];
    int s = 0;
    for (int k = 0; k < 2; ++k) {
        int c = 2 * t + k;
        int cv = (c < N_CHUNKS) ? hist[c * N_BUCKETS + b] : 0;
        v[k] = s;
        s += cv;
    }
    lds[t] = s;
    __syncthreads();
    for (int off = 1; off < 256; off <<= 1) {
        int val = (t >= off) ? lds[t - off] : 0;
        __syncthreads();
        lds[t] += val;
        __syncthreads();
    }
    int excl = (t == 0) ? 0 : lds[t - 1];
    for (int k = 0; k < 2; ++k) {
        int c = 2 * t + k;
        if (c < N_CHUNKS) base[b * N_CHUNKS + c] = excl + v[k];
    }
    if (t == 255) bucketTotal[b] = lds[255];
}

// 3) exclusive scan over 782 bucket totals -> bucketBase
__global__ __launch_bounds__(256) void scan_buckets_kernel(const int* __restrict__ bucketTotal,
                                                           int* __restrict__ bucketBase) {
    __shared__ int lds[256];
    int t = threadIdx.x;
    int v[4];
    int s = 0;
    for (int k = 0; k < 4; ++k) {
        int b = 4 * t + k;
        int cv = (b < N_BUCKETS) ? bucketTotal[b] : 0;
        v[k] = s;
        s += cv;
    }
    lds[t] = s;
    __syncthreads();
    for (int off = 1; off < 256; off <<= 1) {
        int val = (t >= off) ? lds[t - off] : 0;
        __syncthreads();
        lds[t] += val;
        __syncthreads();
    }
    int excl = (t == 0) ? 0 : lds[t - 1];
    for (int k = 0; k < 4; ++k) {
        int b = 4 * t + k;
        if (b < N_BUCKETS) bucketBase[b] = excl + v[k];
    }
}

// 4) deterministic scatter into bucket-grouped stage; LDS slice counters only.
__global__ __launch_bounds__(256) void scatter_kernel(const int* __restrict__ src,
                                                      const int* __restrict__ dst,
                                                      const int* __restrict__ base,
                                                      const int* __restrict__ bucketBase,
                                                      int* __restrict__ stage) {
    __shared__ int lbase[N_BUCKETS];
    __shared__ int lcnt[N_BUCKETS];
    int bid = blockIdx.x;
    int chunk = (bid & 7) * 49 + (bid >> 3);   // bijection on [0,392)
    int t = threadIdx.x;
    for (int b = t; b < N_BUCKETS; b += 256) {
        lbase[b] = base[b * N_CHUNKS + chunk] + bucketBase[b];
        lcnt[b] = 0;
    }
    __syncthreads();
    int e0 = chunk * CHUNK;
    for (int i = t; i < CHUNK; i += 256) {
        int e = e0 + i;
        if (e < N_EDGES) {
            int d = dst[e];
            int b = d >> BUCKET_SHIFT;
            int pos = lbase[b] + atomicAdd(&lcnt[b], 1);
            stage[pos] = ((d & (BUCKET_NODES - 1)) << 17) | src[e];
        }
    }
}

// 5) one block per bucket: LDS node histogram + scan -> row_start/cnt/dinv + csr place
__global__ __launch_bounds__(256) void place_kernel(const int* __restrict__ stage,
                                                    const int* __restrict__ bucketBase,
                                                    int* __restrict__ csr,
                                                    int* __restrict__ row_start,
                                                    int* __restrict__ cnt,
                                                    float* __restrict__ dinv) {
    __shared__ int lhist[BUCKET_NODES];
    __shared__ int lscan[BUCKET_NODES];
    __shared__ int lstart[BUCKET_NODES];
    __shared__ int lcur[BUCKET_NODES];
    int b = blockIdx.x;
    int t = threadIdx.x;
    int est = bucketBase[b];
    int een = (b == N_BUCKETS - 1) ? N_EDGES : bucketBase[b + 1];
    if (t < BUCKET_NODES) { lhist[t] = 0; lcur[t] = 0; }
    __syncthreads();
    for (int e = est + t; e < een; e += 256) atomicAdd(&lhist[stage[e] >> 17], 1);
    __syncthreads();
    if (t < BUCKET_NODES) lscan[t] = lhist[t];
    __syncthreads();
    for (int off = 1; off < BUCKET_NODES; off <<= 1) {
        int val = (t >= off && t < BUCKET_NODES) ? lscan[t - off] : 0;
        __syncthreads();
        if (t < BUCKET_NODES) lscan[t] += val;
        __syncthreads();
    }
    if (t < BUCKET_NODES) {
        int myexcl = (t == 0) ? 0 : lscan[t - 1];
        lstart[t] = est + myexcl;
        int node = (b << BUCKET_SHIFT) + t;
        if (node < N_NODES) {
            row_start[node] = est + myexcl;
            cnt[node] = lhist[t];
            dinv[node] = rsqrtf((float)lhist[t] + 1.0f);
        }
    }
    __syncthreads();
    for (int e = est + t; e < een; e += 256) {
        int rec = stage[e];
        int dl = rec >> 17;
        int pos = lstart[dl] + atomicAdd(&lcur[dl], 1);
        csr[pos] = rec & 0x1FFFF;
    }
}

// ---- W1,W2 -> fragment-ordered f16 (B-operand layout for mfma_f32_16x16x32_f16) ----
__global__ __launch_bounds__(256) void wfrag_kernel(const float* __restrict__ W1,
                                                    const float* __restrict__ W2,
                                                    f16* __restrict__ w1f,
                                                    f16* __restrict__ w2f) {
    int g = blockIdx.x * 256 + threadIdx.x;
    if (g < 1024) {
        int f = g >> 6, L = g & 63;
        int s = f >> 2, c = f & 3;
        int q = L >> 4, n = L & 15;
        f16x8 v;
#pragma unroll
        for (int j = 0; j < 8; ++j) v[j] = (f16)W1[(32 * s + 8 * q + j) * HID_DIM + 16 * c + n];
        *(f16x8*)&w1f[(size_t)g * 8] = v;
    } else if (g < 1024 + 384) {
        int gg = g - 1024;
        int f = gg >> 6, L = gg & 63;
        int s = f / 3, c = f % 3;
        int q = L >> 4, n = L & 15;
        int col = 16 * c + n;
        f16x8 v;
#pragma unroll
        for (int j = 0; j < 8; ++j)
            v[j] = (col < OUT_DIM) ? (f16)W2[(32 * s + 8 * q + j) * OUT_DIM + col] : (f16)0.f;
        *(f16x8*)&w2f[(size_t)gg * 8] = v;
    }
}

// ---------------- gemm1 (MFMA): h1p = f16( dinv * (x @ W1) ) ----------------
__global__ __launch_bounds__(256) void gemm1_kernel(const float* __restrict__ x,
                                                    const f16* __restrict__ w1f,
                                                    const float* __restrict__ dinv,
                                                    f16* __restrict__ h1p) {
    __shared__ f16 aT[1088 * 8];   // 17408 B
    int t = threadIdx.x;
    int nodeBase = blockIdx.x * 64;
    int L = t & 63;

    const f16x8* w1f8 = (const f16x8*)w1f;
    f16x8 bfrag[16];
#pragma unroll
    for (int f = 0; f < 16; ++f) bfrag[f] = w1f8[f * 64 + L];

#pragma unroll
    for (int i = 0; i < 8; ++i) {
        int idx = i * 256 + t;
        int node = idx >> 5;
        int col4 = idx & 31;
        int gnode = nodeBase + node;
        if (gnode >= N_NODES) gnode = N_NODES - 1;
        float4 v = *(const float4*)&x[(size_t)gnode * IN_DIM + col4 * 4];
        int w = node >> 4, m = node & 15;
        int s = col4 >> 3, q = (col4 >> 1) & 3, j0 = (col4 & 1) * 4;
        f16x4 h;
        h.x = (f16)v.x; h.y = (f16)v.y; h.z = (f16)v.z; h.w = (f16)v.w;
        int idx16 = (w * 4 + s) * 68 + 17 * q + m;
        *(f16x4*)&aT[idx16 * 8 + j0] = h;
    }
    __syncthreads();

    int wv = t >> 6;
    int q = L >> 4, m = L & 15;
    f32x4 acc[4] = {};
#pragma unroll
    for (int s = 0; s < 4; ++s) {
        f16x8 afrag = *(const f16x8*)&aT[((wv * 4 + s) * 68 + 17 * q + m) * 8];
#pragma unroll
        for (int c = 0; c < 4; ++c)
            acc[c] = __builtin_amdgcn_mfma_f32_16x16x32_f16(afrag, bfrag[s * 4 + c], acc[c], 0, 0, 0);
    }

#pragma unroll
    for (int r = 0; r < 4; ++r) {
        int node = nodeBase + 16 * wv + q * 4 + r;
        if (node < N_NODES) {
            float di = dinv[node];
#pragma unroll
            for (int c = 0; c < 4; ++c)
                h1p[(size_t)node * HID_DIM + 16 * c + m] = (f16)(acc[c][r] * di);
        }
    }
}

// ---------------- fused agg1 + gemm2 ----------------
// Phase 1: gather (unroll 8, 8-index prefetch); Phase 2: MFMA z @ W2 -> h2p.
#define ZSTR 72
__global__ __launch_bounds__(256) void agg1mm_kernel(const f16* __restrict__ h1p,
                                                     const int* __restrict__ csr,
                                                     const int* __restrict__ row_start,
                                                     const int* __restrict__ cnt,
                                                     const float* __restrict__ dinv,
                                                     const float* __restrict__ b1,
                                                     const f16* __restrict__ w2f,
                                                     f16* __restrict__ h2p) {
    __shared__ f16 zT[64 * ZSTR];   // 9216 B
    int t = threadIdx.x;
    int nodeBase = blockIdx.x * 64;
    int halfw = t >> 5;             // 0..7
    int lane = t & 31;              // f16x2 slot: dims 2*lane, 2*lane+1
    const f16x2* h = (const f16x2*)h1p;   // row stride 32 f16x2
    float2 bb = *(const float2*)&b1[2 * lane];

    for (int r = 0; r < 8; ++r) {
        int nodeLocal = r * 8 + halfw;
        int node = nodeBase + nodeLocal;
        float2 acc;
        acc.x = 0.f; acc.y = 0.f;
        if (node < N_NODES) {
            f16x2 sv = h[(size_t)node * 32 + lane];   // self loop
            acc.x = (float)sv.x;
            acc.y = (float)sv.y;
            int n = cnt[node];
            const int* cp = csr + row_start[node];
            int k = 0;
            if (n >= 8) {
                int idx[8];
#pragma unroll
                for (int u = 0; u < 8; ++u) idx[u] = cp[u];
                for (; k + 16 <= n; k += 8) {
                    int nidx[8];
#pragma unroll
                    for (int u = 0; u < 8; ++u) nidx[u] = cp[k + 8 + u];
#pragma unroll
                    for (int u = 0; u < 8; ++u) {
                        f16x2 f = h[(size_t)idx[u] * 32 + lane];
                        acc.x += (float)f.x;
                        acc.y += (float)f.y;
                    }
#pragma unroll
                    for (int u = 0; u < 8; ++u) idx[u] = nidx[u];
                }
#pragma unroll
                for (int u = 0; u < 8; ++u) {
                    f16x2 f = h[(size_t)idx[u] * 32 + lane];
                    acc.x += (float)f.x;
                    acc.y += (float)f.y;
                }
                k += 8;
            }
            for (; k < n; ++k) {
                f16x2 f = h[(size_t)cp[k] * 32 + lane];
                acc.x += (float)f.x;
                acc.y += (float)f.y;
            }
            float di = dinv[node];
            float v0 = acc.x * di + bb.x;
            float v1 = acc.y * di + bb.y;
            acc.x = v0 > 0.f ? v0 : 0.f;
            acc.y = v1 > 0.f ? v1 : 0.f;
        }
        f16x2 o;
        o.x = (f16)acc.x;
        o.y = (f16)acc.y;
        *(f16x2*)&zT[nodeLocal * ZSTR + 2 * lane] = o;
    }
    __syncthreads();

    // Phase 2: wave wv -> m-tile wv (nodes nodeBase+16*wv .. +15)
    int wv = t >> 6;
    int L = t & 63;
    int q = L >> 4, m = L & 15;
    const f16x8* w2f8 = (const f16x8*)w2f;
    f32x4 acc2[3] = {};
#pragma unroll
    for (int s = 0; s < 2; ++s) {
        f16x8 afrag = *(const f16x8*)&zT[(16 * wv + m) * ZSTR + 32 * s + 8 * q];
#pragma unroll
        for (int c = 0; c < 3; ++c)
            acc2[c] = __builtin_amdgcn_mfma_f32_16x16x32_f16(afrag, w2f8[(s * 3 + c) * 64 + L], acc2[c], 0, 0, 0);
    }
#pragma unroll
    for (int r = 0; r < 4; ++r) {
        int node = nodeBase + 16 * wv + q * 4 + r;
        if (node < N_NODES) {
            float di = dinv[node];
            h2p[(size_t)node * OUT_DIM + m]      = (f16)(acc2[0][r] * di);
            h2p[(size_t)node * OUT_DIM + 16 + m] = (f16)(acc2[1][r] * di);
            if (m < 8)
                h2p[(size_t)node * OUT_DIM + 32 + m] = (f16)(acc2[2][r] * di);
        }
    }
}

// agg2: 2 nodes per wave (32-lane halves), lanes 0..19 gather f16x2; unroll 8 + prefetch
__global__ __launch_bounds__(256) void agg2_kernel(const f16* __restrict__ h2p,
                                                   const int* __restrict__ csr,
                                                   const int* __restrict__ row_start,
                                                   const int* __restrict__ cnt,
                                                   const float* __restrict__ dinv,
                                                   const float* __restrict__ b2,
                                                   float* __restrict__ out) {
    int node = blockIdx.x * 8 + (threadIdx.x >> 5);
    int lane = threadIdx.x & 31;          // f16x2 slot: dims 2*lane, 2*lane+1 (active <20)
    if (node >= N_NODES || lane >= 20) return;
    const f16x2* h = (const f16x2*)h2p;   // row stride 20 (f16x2 units)
    float2 acc;
    {
        f16x2 sv = h[(size_t)node * 20 + lane];   // self loop
        acc.x = (float)sv.x;
        acc.y = (float)sv.y;
    }
    int n = cnt[node];
    const int* cp = csr + row_start[node];
    int k = 0;
    if (n >= 8) {
        int idx[8];
#pragma unroll
        for (int u = 0; u < 8; ++u) idx[u] = cp[u];
        for (; k + 16 <= n; k += 8) {
            int nidx[8];
#pragma unroll
            for (int u = 0; u < 8; ++u) nidx[u] = cp[k + 8 + u];
#pragma unroll
            for (int u = 0; u < 8; ++u) {
                f16x2 f = h[(size_t)idx[u] * 20 + lane];
                acc.x += (float)f.x;
                acc.y += (float)f.y;
            }
#pragma unroll
            for (int u = 0; u < 8; ++u) idx[u] = nidx[u];
        }
#pragma unroll
        for (int u = 0; u < 8; ++u) {
            f16x2 f = h[(size_t)idx[u] * 20 + lane];
            acc.x += (float)f.x;
            acc.y += (float)f.y;
        }
        k += 8;
    }
    for (; k < n; ++k) {
        f16x2 f = h[(size_t)cp[k] * 20 + lane];
        acc.x += (float)f.x;
        acc.y += (float)f.y;
    }
    float di = dinv[node];
    float2 bb = *(const float2*)&b2[2 * lane];
    float2 o;
    o.x = acc.x * di + bb.x;
    o.y = acc.y * di + bb.y;
    *(float2*)&out[(size_t)node * OUT_DIM + 2 * lane] = o;
}

extern "C" void kernel_launch(void* const* d_in, const int* in_sizes, int n_in,
                              void* d_out, int out_size, void* d_ws, size_t ws_size,
                              hipStream_t stream) {
    const float* x  = (const float*)d_in[0];
    const int*   ei = (const int*)d_in[1];      // [2, E] int32
    const float* W1 = (const float*)d_in[2];
    const float* b1 = (const float*)d_in[3];
    const float* W2 = (const float*)d_in[4];
    const float* b2 = (const float*)d_in[5];
    float* out = (float*)d_out;

    const int* src = ei;
    const int* dst = ei + N_EDGES;

    int* wsi        = (int*)d_ws;
    int* hist       = wsi;
    int* base       = hist + N_CHUNKS * N_BUCKETS;
    int* bucketTotal= base + N_BUCKETS * N_CHUNKS;
    int* bucketBase = bucketTotal + 1024;
    int* row_start  = bucketBase + 1024;
    int* cnt        = row_start + NPAD;
    int* csr        = cnt + NPAD;
    int* stage      = csr + N_EDGES;
    float* dinv     = (float*)(stage + N_EDGES);
    f16*   h1p      = (f16*)(dinv + NPAD);
    f16*   h2p      = h1p + (size_t)N_NODES * HID_DIM;
    f16*   w1f      = h2p + (size_t)N_NODES * OUT_DIM;   // 8192 f16
    f16*   w2f      = w1f + 8192;                        // 3072 f16

    hist_kernel<<<N_CHUNKS, 256, 0, stream>>>(dst, hist);
    scan_chunks_kernel<<<N_BUCKETS, 256, 0, stream>>>(hist, base, bucketTotal);
    scan_buckets_kernel<<<1, 256, 0, stream>>>(bucketTotal, bucketBase);
    scatter_kernel<<<N_CHUNKS, 256, 0, stream>>>(src, dst, base, bucketBase, stage);
    place_kernel<<<N_BUCKETS, 256, 0, stream>>>(stage, bucketBase, csr, row_start, cnt, dinv);

    wfrag_kernel<<<6, 256, 0, stream>>>(W1, W2, w1f, w2f);
    gemm1_kernel<<<(N_NODES + 63) / 64, 256, 0, stream>>>(x, w1f, dinv, h1p);
    agg1mm_kernel<<<(N_NODES + 63) / 64, 256, 0, stream>>>(h1p, csr, row_start, cnt, dinv, b1, w2f, h2p);
    agg2_kernel<<<(N_NODES + 7) / 8, 256, 0, stream>>>(h2p, csr, row_start, cnt, dinv, b2, out);
}

// Round 12
// 217.783 us; speedup vs baseline: 1.1179x; 1.1179x over previous
//
#include <hip/hip_runtime.h>
#include <math.h>

#define N_NODES 100000
#define N_EDGES 1600000
#define IN_DIM 128
#define HID_DIM 64
#define OUT_DIM 40

#define NPAD 102400

#define BUCKET_SHIFT 7
#define BUCKET_NODES 128
#define N_BUCKETS 782          // ceil(100000/128)
#define CHUNK 2048
#define N_CHUNKS 784           // 8 XCD groups x 98; 784*2048 >= N_EDGES

typedef _Float16 f16;
typedef _Float16 f16x2 __attribute__((ext_vector_type(2)));
typedef _Float16 f16x4 __attribute__((ext_vector_type(4)));
typedef _Float16 f16x8 __attribute__((ext_vector_type(8)));
typedef float f32x4 __attribute__((ext_vector_type(4)));

// -------- workspace layout --------
// ints:  hist[N_CHUNKS*N_BUCKETS] | base[N_BUCKETS*N_CHUNKS] | bucketTotal[1024] |
//        bucketBase[1024] | row_start[NPAD] | cnt[NPAD] | csr[E] | stage[E]
// floats: dinv[NPAD]
// f16:    h1p[N*64] | h2p[N*40] | w1f[8192] | w2f[3072]
// NO memset needed: every buffer fully written before read each launch.

// 1) per-chunk LDS histogram over dst buckets; coalesced row write
__global__ __launch_bounds__(256) void hist_kernel(const int* __restrict__ dst,
                                                   int* __restrict__ hist) {
    __shared__ int lh[N_BUCKETS];
    int c = blockIdx.x;
    int t = threadIdx.x;
    for (int b = t; b < N_BUCKETS; b += 256) lh[b] = 0;
    __syncthreads();
    int e0 = c * CHUNK;
    for (int i = t; i < CHUNK; i += 256) {
        int e = e0 + i;
        if (e < N_EDGES) atomicAdd(&lh[dst[e] >> BUCKET_SHIFT], 1);
    }
    __syncthreads();
    for (int b = t; b < N_BUCKETS; b += 256) hist[c * N_BUCKETS + b] = lh[b];
}

// 2) per-bucket exclusive scan over chunks -> base[b][c], bucketTotal[b]
__global__ __launch_bounds__(256) void scan_chunks_kernel(const int* __restrict__ hist,
                                                          int* __restrict__ base,
                                                          int* __restrict__ bucketTotal) {
    __shared__ int lds[256];
    int b = blockIdx.x;
    int t = threadIdx.x;
    int v[4];
    int s = 0;
    for (int k = 0; k < 4; ++k) {
        int c = 4 * t + k;
        int cv = (c < N_CHUNKS) ? hist[c * N_BUCKETS + b] : 0;
        v[k] = s;
        s += cv;
    }
    lds[t] = s;
    __syncthreads();
    for (int off = 1; off < 256; off <<= 1) {
        int val = (t >= off) ? lds[t - off] : 0;
        __syncthreads();
        lds[t] += val;
        __syncthreads();
    }
    int excl = (t == 0) ? 0 : lds[t - 1];
    for (int k = 0; k < 4; ++k) {
        int c = 4 * t + k;
        if (c < N_CHUNKS) base[b * N_CHUNKS + c] = excl + v[k];
    }
    if (t == 255) bucketTotal[b] = lds[255];
}

// 3) exclusive scan over 782 bucket totals -> bucketBase
__global__ __launch_bounds__(256) void scan_buckets_kernel(const int* __restrict__ bucketTotal,
                                                           int* __restrict__ bucketBase) {
    __shared__ int lds[256];
    int t = threadIdx.x;
    int v[4];
    int s = 0;
    for (int k = 0; k < 4; ++k) {
        int b = 4 * t + k;
        int cv = (b < N_BUCKETS) ? bucketTotal[b] : 0;
        v[k] = s;
        s += cv;
    }
    lds[t] = s;
    __syncthreads();
    for (int off = 1; off < 256; off <<= 1) {
        int val = (t >= off) ? lds[t - off] : 0;
        __syncthreads();
        lds[t] += val;
        __syncthreads();
    }
    int excl = (t == 0) ? 0 : lds[t - 1];
    for (int k = 0; k < 4; ++k) {
        int b = 4 * t + k;
        if (b < N_BUCKETS) bucketBase[b] = excl + v[k];
    }
}

// 4) deterministic scatter into bucket-grouped stage; LDS slice counters only.
__global__ __launch_bounds__(256) void scatter_kernel(const int* __restrict__ src,
                                                      const int* __restrict__ dst,
                                                      const int* __restrict__ base,
                                                      const int* __restrict__ bucketBase,
                                                      int* __restrict__ stage) {
    __shared__ int lbase[N_BUCKETS];
    __shared__ int lcnt[N_BUCKETS];
    int bid = blockIdx.x;
    int chunk = (bid & 7) * 98 + (bid >> 3);   // bijection on [0,784)
    int t = threadIdx.x;
    for (int b = t; b < N_BUCKETS; b += 256) {
        lbase[b] = base[b * N_CHUNKS + chunk] + bucketBase[b];
        lcnt[b] = 0;
    }
    __syncthreads();
    int e0 = chunk * CHUNK;
    for (int i = t; i < CHUNK; i += 256) {
        int e = e0 + i;
        if (e < N_EDGES) {
            int d = dst[e];
            int b = d >> BUCKET_SHIFT;
            int pos = lbase[b] + atomicAdd(&lcnt[b], 1);
            stage[pos] = ((d & (BUCKET_NODES - 1)) << 17) | src[e];
        }
    }
}

// 5) one block per bucket: LDS node histogram + scan -> row_start/cnt/dinv + csr place
__global__ __launch_bounds__(256) void place_kernel(const int* __restrict__ stage,
                                                    const int* __restrict__ bucketBase,
                                                    int* __restrict__ csr,
                                                    int* __restrict__ row_start,
                                                    int* __restrict__ cnt,
                                                    float* __restrict__ dinv) {
    __shared__ int lhist[BUCKET_NODES];
    __shared__ int lscan[BUCKET_NODES];
    __shared__ int lstart[BUCKET_NODES];
    __shared__ int lcur[BUCKET_NODES];
    int b = blockIdx.x;
    int t = threadIdx.x;
    int est = bucketBase[b];
    int een = (b == N_BUCKETS - 1) ? N_EDGES : bucketBase[b + 1];
    if (t < BUCKET_NODES) { lhist[t] = 0; lcur[t] = 0; }
    __syncthreads();
    for (int e = est + t; e < een; e += 256) atomicAdd(&lhist[stage[e] >> 17], 1);
    __syncthreads();
    if (t < BUCKET_NODES) lscan[t] = lhist[t];
    __syncthreads();
    for (int off = 1; off < BUCKET_NODES; off <<= 1) {
        int val = (t >= off && t < BUCKET_NODES) ? lscan[t - off] : 0;
        __syncthreads();
        if (t < BUCKET_NODES) lscan[t] += val;
        __syncthreads();
    }
    if (t < BUCKET_NODES) {
        int myexcl = (t == 0) ? 0 : lscan[t - 1];
        lstart[t] = est + myexcl;
        int node = (b << BUCKET_SHIFT) + t;
        if (node < N_NODES) {
            row_start[node] = est + myexcl;
            cnt[node] = lhist[t];
            dinv[node] = rsqrtf((float)lhist[t] + 1.0f);
        }
    }
    __syncthreads();
    for (int e = est + t; e < een; e += 256) {
        int rec = stage[e];
        int dl = rec >> 17;
        int pos = lstart[dl] + atomicAdd(&lcur[dl], 1);
        csr[pos] = rec & 0x1FFFF;
    }
}

// ---- W1,W2 -> fragment-ordered f16 (B-operand layout for mfma_f32_16x16x32_f16) ----
__global__ __launch_bounds__(256) void wfrag_kernel(const float* __restrict__ W1,
                                                    const float* __restrict__ W2,
                                                    f16* __restrict__ w1f,
                                                    f16* __restrict__ w2f) {
    int g = blockIdx.x * 256 + threadIdx.x;
    if (g < 1024) {
        int f = g >> 6, L = g & 63;
        int s = f >> 2, c = f & 3;
        int q = L >> 4, n = L & 15;
        f16x8 v;
#pragma unroll
        for (int j = 0; j < 8; ++j) v[j] = (f16)W1[(32 * s + 8 * q + j) * HID_DIM + 16 * c + n];
        *(f16x8*)&w1f[(size_t)g * 8] = v;
    } else if (g < 1024 + 384) {
        int gg = g - 1024;
        int f = gg >> 6, L = gg & 63;
        int s = f / 3, c = f % 3;
        int q = L >> 4, n = L & 15;
        int col = 16 * c + n;
        f16x8 v;
#pragma unroll
        for (int j = 0; j < 8; ++j)
            v[j] = (col < OUT_DIM) ? (f16)W2[(32 * s + 8 * q + j) * OUT_DIM + col] : (f16)0.f;
        *(f16x8*)&w2f[(size_t)gg * 8] = v;
    }
}

// ---------------- gemm1 (MFMA): h1p = f16( dinv * (x @ W1) ) ----------------
__global__ __launch_bounds__(256) void gemm1_kernel(const float* __restrict__ x,
                                                    const f16* __restrict__ w1f,
                                                    const float* __restrict__ dinv,
                                                    f16* __restrict__ h1p) {
    __shared__ f16 aT[1088 * 8];   // 17408 B
    int t = threadIdx.x;
    int nodeBase = blockIdx.x * 64;
    int L = t & 63;

    const f16x8* w1f8 = (const f16x8*)w1f;
    f16x8 bfrag[16];
#pragma unroll
    for (int f = 0; f < 16; ++f) bfrag[f] = w1f8[f * 64 + L];

#pragma unroll
    for (int i = 0; i < 8; ++i) {
        int idx = i * 256 + t;
        int node = idx >> 5;
        int col4 = idx & 31;
        int gnode = nodeBase + node;
        if (gnode >= N_NODES) gnode = N_NODES - 1;
        float4 v = *(const float4*)&x[(size_t)gnode * IN_DIM + col4 * 4];
        int w = node >> 4, m = node & 15;
        int s = col4 >> 3, q = (col4 >> 1) & 3, j0 = (col4 & 1) * 4;
        f16x4 h;
        h.x = (f16)v.x; h.y = (f16)v.y; h.z = (f16)v.z; h.w = (f16)v.w;
        int idx16 = (w * 4 + s) * 68 + 17 * q + m;
        *(f16x4*)&aT[idx16 * 8 + j0] = h;
    }
    __syncthreads();

    int wv = t >> 6;
    int q = L >> 4, m = L & 15;
    f32x4 acc[4] = {};
#pragma unroll
    for (int s = 0; s < 4; ++s) {
        f16x8 afrag = *(const f16x8*)&aT[((wv * 4 + s) * 68 + 17 * q + m) * 8];
#pragma unroll
        for (int c = 0; c < 4; ++c)
            acc[c] = __builtin_amdgcn_mfma_f32_16x16x32_f16(afrag, bfrag[s * 4 + c], acc[c], 0, 0, 0);
    }

#pragma unroll
    for (int r = 0; r < 4; ++r) {
        int node = nodeBase + 16 * wv + q * 4 + r;
        if (node < N_NODES) {
            float di = dinv[node];
#pragma unroll
            for (int c = 0; c < 4; ++c)
                h1p[(size_t)node * HID_DIM + 16 * c + m] = (f16)(acc[c][r] * di);
        }
    }
}

// ---------------- fused agg1 + gemm2 ----------------
// Phase 1: 4 nodes per wave concurrently (16-lane groups, lane reads f16x4=8B;
// one group = one 128B row) -> 16 rows in flight per wave with unroll-4.
// Masked tail (clamped idx + 0/1 mask) -> no serial scalar tail. Divergent loop
// bound per group: finished groups' loads are exec-masked off.
// Phase 2: MFMA z @ W2 (cols zero-padded to 48) -> h2p.
#define ZSTR 72
__global__ __launch_bounds__(256) void agg1mm_kernel(const f16* __restrict__ h1p,
                                                     const int* __restrict__ csr,
                                                     const int* __restrict__ row_start,
                                                     const int* __restrict__ cnt,
                                                     const float* __restrict__ dinv,
                                                     const float* __restrict__ b1,
                                                     const f16* __restrict__ w2f,
                                                     f16* __restrict__ h2p) {
    __shared__ f16 zT[64 * ZSTR];   // 9216 B
    int t = threadIdx.x;
    int nodeBase = blockIdx.x * 64;
    int wv = t >> 6;
    int L = t & 63;
    int g = L >> 4;       // node group 0..3 within wave
    int s = L & 15;       // sublane: f16x4 slot (dims 4s..4s+3)
    const f16x4* h4 = (const f16x4*)h1p;   // row stride 16 (f16x4 units)
    float4 bb = *(const float4*)&b1[4 * s];

    for (int p = 0; p < 4; ++p) {
        int nodeLocal = 16 * wv + 4 * p + g;
        int node = nodeBase + nodeLocal;
        float4 acc;
        acc.x = 0.f; acc.y = 0.f; acc.z = 0.f; acc.w = 0.f;
        int lim = 0;
        const int* cp = csr;
        bool valid = (node < N_NODES);
        if (valid) {
            f16x4 sv = h4[(size_t)node * 16 + s];   // self loop
            acc.x = (float)sv.x; acc.y = (float)sv.y;
            acc.z = (float)sv.z; acc.w = (float)sv.w;
            lim = cnt[node];
            cp = csr + row_start[node];
        }
        for (int k = 0; k < lim; k += 4) {
            int k1 = (k + 1 < lim) ? k + 1 : k;
            int k2 = (k + 2 < lim) ? k + 2 : k;
            int k3 = (k + 3 < lim) ? k + 3 : k;
            int i0 = cp[k], i1 = cp[k1], i2 = cp[k2], i3 = cp[k3];
            f16x4 f0 = h4[(size_t)i0 * 16 + s];
            f16x4 f1 = h4[(size_t)i1 * 16 + s];
            f16x4 f2 = h4[(size_t)i2 * 16 + s];
            f16x4 f3 = h4[(size_t)i3 * 16 + s];
            float m1 = (k + 1 < lim) ? 1.f : 0.f;
            float m2 = (k + 2 < lim) ? 1.f : 0.f;
            float m3 = (k + 3 < lim) ? 1.f : 0.f;
            acc.x += (float)f0.x + m1 * (float)f1.x + m2 * (float)f2.x + m3 * (float)f3.x;
            acc.y += (float)f0.y + m1 * (float)f1.y + m2 * (float)f2.y + m3 * (float)f3.y;
            acc.z += (float)f0.z + m1 * (float)f1.z + m2 * (float)f2.z + m3 * (float)f3.z;
            acc.w += (float)f0.w + m1 * (float)f1.w + m2 * (float)f2.w + m3 * (float)f3.w;
        }
        f16x4 o;
        if (valid) {
            float di = dinv[node];
            float v0 = acc.x * di + bb.x;
            float v1 = acc.y * di + bb.y;
            float v2 = acc.z * di + bb.z;
            float v3 = acc.w * di + bb.w;
            o.x = (f16)(v0 > 0.f ? v0 : 0.f);
            o.y = (f16)(v1 > 0.f ? v1 : 0.f);
            o.z = (f16)(v2 > 0.f ? v2 : 0.f);
            o.w = (f16)(v3 > 0.f ? v3 : 0.f);
        } else {
            o.x = (f16)0.f; o.y = (f16)0.f; o.z = (f16)0.f; o.w = (f16)0.f;
        }
        *(f16x4*)&zT[nodeLocal * ZSTR + 4 * s] = o;
    }
    __syncthreads();

    // Phase 2: wave wv -> m-tile wv (nodes nodeBase+16*wv .. +15)
    int q = L >> 4, m = L & 15;
    const f16x8* w2f8 = (const f16x8*)w2f;
    f32x4 acc2[3] = {};
#pragma unroll
    for (int ks = 0; ks < 2; ++ks) {
        f16x8 afrag = *(const f16x8*)&zT[(16 * wv + m) * ZSTR + 32 * ks + 8 * q];
#pragma unroll
        for (int c = 0; c < 3; ++c)
            acc2[c] = __builtin_amdgcn_mfma_f32_16x16x32_f16(afrag, w2f8[(ks * 3 + c) * 64 + L], acc2[c], 0, 0, 0);
    }
#pragma unroll
    for (int r = 0; r < 4; ++r) {
        int node = nodeBase + 16 * wv + q * 4 + r;
        if (node < N_NODES) {
            float di = dinv[node];
            h2p[(size_t)node * OUT_DIM + m]      = (f16)(acc2[0][r] * di);
            h2p[(size_t)node * OUT_DIM + 16 + m] = (f16)(acc2[1][r] * di);
            if (m < 8)
                h2p[(size_t)node * OUT_DIM + 32 + m] = (f16)(acc2[2][r] * di);
        }
    }
}

// agg2: 1 node per 16-lane group (lanes 0..9 carry the 80B row as f16x4),
// 16 groups per block; unroll-4 with masked tail -> 16 rows in flight per wave.
__global__ __launch_bounds__(256) void agg2_kernel(const f16* __restrict__ h2p,
                                                   const int* __restrict__ csr,
                                                   const int* __restrict__ row_start,
                                                   const int* __restrict__ cnt,
                                                   const float* __restrict__ dinv,
                                                   const float* __restrict__ b2,
                                                   float* __restrict__ out) {
    int t = threadIdx.x;
    int node = blockIdx.x * 16 + (t >> 4);
    int s = t & 15;                       // f16x4 slot: dims 4s..4s+3 (active s<10)
    if (node >= N_NODES || s >= 10) return;
    const f16x4* h4 = (const f16x4*)h2p;  // row stride 10 (f16x4 units)
    float4 acc;
    {
        f16x4 sv = h4[(size_t)node * 10 + s];   // self loop
        acc.x = (float)sv.x; acc.y = (float)sv.y;
        acc.z = (float)sv.z; acc.w = (float)sv.w;
    }
    int lim = cnt[node];
    const int* cp = csr + row_start[node];
    for (int k = 0; k < lim; k += 4) {
        int k1 = (k + 1 < lim) ? k + 1 : k;
        int k2 = (k + 2 < lim) ? k + 2 : k;
        int k3 = (k + 3 < lim) ? k + 3 : k;
        int i0 = cp[k], i1 = cp[k1], i2 = cp[k2], i3 = cp[k3];
        f16x4 f0 = h4[(size_t)i0 * 10 + s];
        f16x4 f1 = h4[(size_t)i1 * 10 + s];
        f16x4 f2 = h4[(size_t)i2 * 10 + s];
        f16x4 f3 = h4[(size_t)i3 * 10 + s];
        float m1 = (k + 1 < lim) ? 1.f : 0.f;
        float m2 = (k + 2 < lim) ? 1.f : 0.f;
        float m3 = (k + 3 < lim) ? 1.f : 0.f;
        acc.x += (float)f0.x + m1 * (float)f1.x + m2 * (float)f2.x + m3 * (float)f3.x;
        acc.y += (float)f0.y + m1 * (float)f1.y + m2 * (float)f2.y + m3 * (float)f3.y;
        acc.z += (float)f0.z + m1 * (float)f1.z + m2 * (float)f2.z + m3 * (float)f3.z;
        acc.w += (float)f0.w + m1 * (float)f1.w + m2 * (float)f2.w + m3 * (float)f3.w;
    }
    float di = dinv[node];
    float4 bb = *(const float4*)&b2[4 * s];
    float4 o;
    o.x = acc.x * di + bb.x;
    o.y = acc.y * di + bb.y;
    o.z = acc.z * di + bb.z;
    o.w = acc.w * di + bb.w;
    *(float4*)&out[(size_t)node * OUT_DIM + 4 * s] = o;
}

extern "C" void kernel_launch(void* const* d_in, const int* in_sizes, int n_in,
                              void* d_out, int out_size, void* d_ws, size_t ws_size,
                              hipStream_t stream) {
    const float* x  = (const float*)d_in[0];
    const int*   ei = (const int*)d_in[1];      // [2, E] int32
    const float* W1 = (const float*)d_in[2];
    const float* b1 = (const float*)d_in[3];
    const float* W2 = (const float*)d_in[4];
    const float* b2 = (const float*)d_in[5];
    float* out = (float*)d_out;

    const int* src = ei;
    const int* dst = ei + N_EDGES;

    int* wsi        = (int*)d_ws;
    int* hist       = wsi;
    int* base       = hist + N_CHUNKS * N_BUCKETS;
    int* bucketTotal= base + N_BUCKETS * N_CHUNKS;
    int* bucketBase = bucketTotal + 1024;
    int* row_start  = bucketBase + 1024;
    int* cnt        = row_start + NPAD;
    int* csr        = cnt + NPAD;
    int* stage      = csr + N_EDGES;
    float* dinv     = (float*)(stage + N_EDGES);
    f16*   h1p      = (f16*)(dinv + NPAD);
    f16*   h2p      = h1p + (size_t)N_NODES * HID_DIM;
    f16*   w1f      = h2p + (size_t)N_NODES * OUT_DIM;   // 8192 f16
    f16*   w2f      = w1f + 8192;                        // 3072 f16

    hist_kernel<<<N_CHUNKS, 256, 0, stream>>>(dst, hist);
    scan_chunks_kernel<<<N_BUCKETS, 256, 0, stream>>>(hist, base, bucketTotal);
    scan_buckets_kernel<<<1, 256, 0, stream>>>(bucketTotal, bucketBase);
    scatter_kernel<<<N_CHUNKS, 256, 0, stream>>>(src, dst, base, bucketBase, stage);
    place_kernel<<<N_BUCKETS, 256, 0, stream>>>(stage, bucketBase, csr, row_start, cnt, dinv);

    wfrag_kernel<<<6, 256, 0, stream>>>(W1, W2, w1f, w2f);
    gemm1_kernel<<<(N_NODES + 63) / 64, 256, 0, stream>>>(x, w1f, dinv, h1p);
    agg1mm_kernel<<<(N_NODES + 63) / 64, 256, 0, stream>>>(h1p, csr, row_start, cnt, dinv, b1, w2f, h2p);
    agg2_kernel<<<(N_NODES + 15) / 16, 256, 0, stream>>>(h2p, csr, row_start, cnt, dinv, b2, out);
}

// Round 13
// 217.309 us; speedup vs baseline: 1.1203x; 1.0022x over previous
//
#include <hip/hip_runtime.h>
#include <math.h>

#define N_NODES 100000
#define N_EDGES 1600000
#define IN_DIM 128
#define HID_DIM 64
#define OUT_DIM 40

#define NPAD 102400

#define BUCKET_SHIFT 7
#define BUCKET_NODES 128
#define N_BUCKETS 782          // ceil(100000/128)
#define CHUNK 2048
#define N_CHUNKS 784           // 8 XCD groups x 98; 784*2048 >= N_EDGES

typedef _Float16 f16;
typedef _Float16 f16x2 __attribute__((ext_vector_type(2)));
typedef _Float16 f16x4 __attribute__((ext_vector_type(4)));
typedef _Float16 f16x8 __attribute__((ext_vector_type(8)));
typedef float f32x4 __attribute__((ext_vector_type(4)));

// -------- workspace layout --------
// ints:  hist[N_CHUNKS*N_BUCKETS] | base[N_BUCKETS*N_CHUNKS] | bucketTotal[1024] |
//        bucketBase[1024] | row_start[NPAD] | cnt[NPAD] | csr[E] | stage[E]
// floats: dinv[NPAD]
// f16:    h1p[N*64] | h2p[N*40] | w1f[8192] | w2f[3072]
// NO memset needed: every buffer fully written before read each launch.

// 1) per-chunk LDS histogram over dst buckets; coalesced row write
__global__ __launch_bounds__(256) void hist_kernel(const int* __restrict__ dst,
                                                   int* __restrict__ hist) {
    __shared__ int lh[N_BUCKETS];
    int c = blockIdx.x;
    int t = threadIdx.x;
    for (int b = t; b < N_BUCKETS; b += 256) lh[b] = 0;
    __syncthreads();
    int e0 = c * CHUNK;
    for (int i = t; i < CHUNK; i += 256) {
        int e = e0 + i;
        if (e < N_EDGES) atomicAdd(&lh[dst[e] >> BUCKET_SHIFT], 1);
    }
    __syncthreads();
    for (int b = t; b < N_BUCKETS; b += 256) hist[c * N_BUCKETS + b] = lh[b];
}

// 2) per-bucket exclusive scan over chunks -> base[b][c], bucketTotal[b]
__global__ __launch_bounds__(256) void scan_chunks_kernel(const int* __restrict__ hist,
                                                          int* __restrict__ base,
                                                          int* __restrict__ bucketTotal) {
    __shared__ int lds[256];
    int b = blockIdx.x;
    int t = threadIdx.x;
    int v[4];
    int s = 0;
    for (int k = 0; k < 4; ++k) {
        int c = 4 * t + k;
        int cv = (c < N_CHUNKS) ? hist[c * N_BUCKETS + b] : 0;
        v[k] = s;
        s += cv;
    }
    lds[t] = s;
    __syncthreads();
    for (int off = 1; off < 256; off <<= 1) {
        int val = (t >= off) ? lds[t - off] : 0;
        __syncthreads();
        lds[t] += val;
        __syncthreads();
    }
    int excl = (t == 0) ? 0 : lds[t - 1];
    for (int k = 0; k < 4; ++k) {
        int c = 4 * t + k;
        if (c < N_CHUNKS) base[b * N_CHUNKS + c] = excl + v[k];
    }
    if (t == 255) bucketTotal[b] = lds[255];
}

// 3) exclusive scan over 782 bucket totals -> bucketBase
__global__ __launch_bounds__(256) void scan_buckets_kernel(const int* __restrict__ bucketTotal,
                                                           int* __restrict__ bucketBase) {
    __shared__ int lds[256];
    int t = threadIdx.x;
    int v[4];
    int s = 0;
    for (int k = 0; k < 4; ++k) {
        int b = 4 * t + k;
        int cv = (b < N_BUCKETS) ? bucketTotal[b] : 0;
        v[k] = s;
        s += cv;
    }
    lds[t] = s;
    __syncthreads();
    for (int off = 1; off < 256; off <<= 1) {
        int val = (t >= off) ? lds[t - off] : 0;
        __syncthreads();
        lds[t] += val;
        __syncthreads();
    }
    int excl = (t == 0) ? 0 : lds[t - 1];
    for (int k = 0; k < 4; ++k) {
        int b = 4 * t + k;
        if (b < N_BUCKETS) bucketBase[b] = excl + v[k];
    }
}

// 4) deterministic scatter into bucket-grouped stage; LDS slice counters only.
__global__ __launch_bounds__(256) void scatter_kernel(const int* __restrict__ src,
                                                      const int* __restrict__ dst,
                                                      const int* __restrict__ base,
                                                      const int* __restrict__ bucketBase,
                                                      int* __restrict__ stage) {
    __shared__ int lbase[N_BUCKETS];
    __shared__ int lcnt[N_BUCKETS];
    int bid = blockIdx.x;
    int chunk = (bid & 7) * 98 + (bid >> 3);   // bijection on [0,784)
    int t = threadIdx.x;
    for (int b = t; b < N_BUCKETS; b += 256) {
        lbase[b] = base[b * N_CHUNKS + chunk] + bucketBase[b];
        lcnt[b] = 0;
    }
    __syncthreads();
    int e0 = chunk * CHUNK;
    for (int i = t; i < CHUNK; i += 256) {
        int e = e0 + i;
        if (e < N_EDGES) {
            int d = dst[e];
            int b = d >> BUCKET_SHIFT;
            int pos = lbase[b] + atomicAdd(&lcnt[b], 1);
            stage[pos] = ((d & (BUCKET_NODES - 1)) << 17) | src[e];
        }
    }
}

// 5) one block per bucket: LDS node histogram + scan -> row_start/cnt/dinv + csr place
__global__ __launch_bounds__(256) void place_kernel(const int* __restrict__ stage,
                                                    const int* __restrict__ bucketBase,
                                                    int* __restrict__ csr,
                                                    int* __restrict__ row_start,
                                                    int* __restrict__ cnt,
                                                    float* __restrict__ dinv) {
    __shared__ int lhist[BUCKET_NODES];
    __shared__ int lscan[BUCKET_NODES];
    __shared__ int lstart[BUCKET_NODES];
    __shared__ int lcur[BUCKET_NODES];
    int b = blockIdx.x;
    int t = threadIdx.x;
    int est = bucketBase[b];
    int een = (b == N_BUCKETS - 1) ? N_EDGES : bucketBase[b + 1];
    if (t < BUCKET_NODES) { lhist[t] = 0; lcur[t] = 0; }
    __syncthreads();
    for (int e = est + t; e < een; e += 256) atomicAdd(&lhist[stage[e] >> 17], 1);
    __syncthreads();
    if (t < BUCKET_NODES) lscan[t] = lhist[t];
    __syncthreads();
    for (int off = 1; off < BUCKET_NODES; off <<= 1) {
        int val = (t >= off && t < BUCKET_NODES) ? lscan[t - off] : 0;
        __syncthreads();
        if (t < BUCKET_NODES) lscan[t] += val;
        __syncthreads();
    }
    if (t < BUCKET_NODES) {
        int myexcl = (t == 0) ? 0 : lscan[t - 1];
        lstart[t] = est + myexcl;
        int node = (b << BUCKET_SHIFT) + t;
        if (node < N_NODES) {
            row_start[node] = est + myexcl;
            cnt[node] = lhist[t];
            dinv[node] = rsqrtf((float)lhist[t] + 1.0f);
        }
    }
    __syncthreads();
    for (int e = est + t; e < een; e += 256) {
        int rec = stage[e];
        int dl = rec >> 17;
        int pos = lstart[dl] + atomicAdd(&lcur[dl], 1);
        csr[pos] = rec & 0x1FFFF;
    }
}

// ---- W1,W2 -> fragment-ordered f16 (B-operand layout for mfma_f32_16x16x32_f16) ----
__global__ __launch_bounds__(256) void wfrag_kernel(const float* __restrict__ W1,
                                                    const float* __restrict__ W2,
                                                    f16* __restrict__ w1f,
                                                    f16* __restrict__ w2f) {
    int g = blockIdx.x * 256 + threadIdx.x;
    if (g < 1024) {
        int f = g >> 6, L = g & 63;
        int s = f >> 2, c = f & 3;
        int q = L >> 4, n = L & 15;
        f16x8 v;
#pragma unroll
        for (int j = 0; j < 8; ++j) v[j] = (f16)W1[(32 * s + 8 * q + j) * HID_DIM + 16 * c + n];
        *(f16x8*)&w1f[(size_t)g * 8] = v;
    } else if (g < 1024 + 384) {
        int gg = g - 1024;
        int f = gg >> 6, L = gg & 63;
        int s = f / 3, c = f % 3;
        int q = L >> 4, n = L & 15;
        int col = 16 * c + n;
        f16x8 v;
#pragma unroll
        for (int j = 0; j < 8; ++j)
            v[j] = (col < OUT_DIM) ? (f16)W2[(32 * s + 8 * q + j) * OUT_DIM + col] : (f16)0.f;
        *(f16x8*)&w2f[(size_t)gg * 8] = v;
    }
}

// ---------------- gemm1 (MFMA): h1p = f16( dinv * (x @ W1) ) ----------------
__global__ __launch_bounds__(256) void gemm1_kernel(const float* __restrict__ x,
                                                    const f16* __restrict__ w1f,
                                                    const float* __restrict__ dinv,
                                                    f16* __restrict__ h1p) {
    __shared__ f16 aT[1088 * 8];   // 17408 B
    int t = threadIdx.x;
    int nodeBase = blockIdx.x * 64;
    int L = t & 63;

    const f16x8* w1f8 = (const f16x8*)w1f;
    f16x8 bfrag[16];
#pragma unroll
    for (int f = 0; f < 16; ++f) bfrag[f] = w1f8[f * 64 + L];

#pragma unroll
    for (int i = 0; i < 8; ++i) {
        int idx = i * 256 + t;
        int node = idx >> 5;
        int col4 = idx & 31;
        int gnode = nodeBase + node;
        if (gnode >= N_NODES) gnode = N_NODES - 1;
        float4 v = *(const float4*)&x[(size_t)gnode * IN_DIM + col4 * 4];
        int w = node >> 4, m = node & 15;
        int s = col4 >> 3, q = (col4 >> 1) & 3, j0 = (col4 & 1) * 4;
        f16x4 h;
        h.x = (f16)v.x; h.y = (f16)v.y; h.z = (f16)v.z; h.w = (f16)v.w;
        int idx16 = (w * 4 + s) * 68 + 17 * q + m;
        *(f16x4*)&aT[idx16 * 8 + j0] = h;
    }
    __syncthreads();

    int wv = t >> 6;
    int q = L >> 4, m = L & 15;
    f32x4 acc[4] = {};
#pragma unroll
    for (int s = 0; s < 4; ++s) {
        f16x8 afrag = *(const f16x8*)&aT[((wv * 4 + s) * 68 + 17 * q + m) * 8];
#pragma unroll
        for (int c = 0; c < 4; ++c)
            acc[c] = __builtin_amdgcn_mfma_f32_16x16x32_f16(afrag, bfrag[s * 4 + c], acc[c], 0, 0, 0);
    }

#pragma unroll
    for (int r = 0; r < 4; ++r) {
        int node = nodeBase + 16 * wv + q * 4 + r;
        if (node < N_NODES) {
            float di = dinv[node];
#pragma unroll
            for (int c = 0; c < 4; ++c)
                h1p[(size_t)node * HID_DIM + 16 * c + m] = (f16)(acc[c][r] * di);
        }
    }
}

// ---------------- fused agg1 + gemm2 ----------------
// Phase 1: 8 nodes per wave concurrently (8-lane groups, lane reads f16x8=16B;
// one group = one 128B row) -> 32 rows in flight per wave with unroll-4.
// Masked tail (clamped idx + 0/1 mask) -> no serial scalar tail.
// Phase 2: MFMA z @ W2 (cols zero-padded to 48) -> h2p.
#define ZSTR 72
__global__ __launch_bounds__(256) void agg1mm_kernel(const f16* __restrict__ h1p,
                                                     const int* __restrict__ csr,
                                                     const int* __restrict__ row_start,
                                                     const int* __restrict__ cnt,
                                                     const float* __restrict__ dinv,
                                                     const float* __restrict__ b1,
                                                     const f16* __restrict__ w2f,
                                                     f16* __restrict__ h2p) {
    __shared__ f16 zT[64 * ZSTR];   // 9216 B
    int t = threadIdx.x;
    int nodeBase = blockIdx.x * 64;
    int wv = t >> 6;
    int L = t & 63;
    int g = L >> 3;       // node group 0..7 within wave
    int s = L & 7;        // sublane: f16x8 slot (dims 8s..8s+7)
    const f16x8* h8 = (const f16x8*)h1p;   // row stride 8 (f16x8 units)
    float bb[8];
#pragma unroll
    for (int j = 0; j < 8; ++j) bb[j] = b1[8 * s + j];

    for (int p = 0; p < 2; ++p) {
        int nodeLocal = 16 * wv + 8 * p + g;
        int node = nodeBase + nodeLocal;
        float acc[8];
#pragma unroll
        for (int j = 0; j < 8; ++j) acc[j] = 0.f;
        int lim = 0;
        const int* cp = csr;
        bool valid = (node < N_NODES);
        if (valid) {
            f16x8 sv = h8[(size_t)node * 8 + s];   // self loop
#pragma unroll
            for (int j = 0; j < 8; ++j) acc[j] = (float)sv[j];
            lim = cnt[node];
            cp = csr + row_start[node];
        }
        for (int k = 0; k < lim; k += 4) {
            int k1 = (k + 1 < lim) ? k + 1 : k;
            int k2 = (k + 2 < lim) ? k + 2 : k;
            int k3 = (k + 3 < lim) ? k + 3 : k;
            int i0 = cp[k], i1 = cp[k1], i2 = cp[k2], i3 = cp[k3];
            f16x8 f0 = h8[(size_t)i0 * 8 + s];
            f16x8 f1 = h8[(size_t)i1 * 8 + s];
            f16x8 f2 = h8[(size_t)i2 * 8 + s];
            f16x8 f3 = h8[(size_t)i3 * 8 + s];
            float m1 = (k + 1 < lim) ? 1.f : 0.f;
            float m2 = (k + 2 < lim) ? 1.f : 0.f;
            float m3 = (k + 3 < lim) ? 1.f : 0.f;
#pragma unroll
            for (int j = 0; j < 8; ++j)
                acc[j] += (float)f0[j] + m1 * (float)f1[j] + m2 * (float)f2[j] + m3 * (float)f3[j];
        }
        f16x8 o;
        if (valid) {
            float di = dinv[node];
#pragma unroll
            for (int j = 0; j < 8; ++j) {
                float v = acc[j] * di + bb[j];
                o[j] = (f16)(v > 0.f ? v : 0.f);
            }
        } else {
#pragma unroll
            for (int j = 0; j < 8; ++j) o[j] = (f16)0.f;
        }
        *(f16x8*)&zT[nodeLocal * ZSTR + 8 * s] = o;
    }
    __syncthreads();

    // Phase 2: wave wv -> m-tile wv (nodes nodeBase+16*wv .. +15)
    int q = L >> 4, m = L & 15;
    const f16x8* w2f8 = (const f16x8*)w2f;
    f32x4 acc2[3] = {};
#pragma unroll
    for (int ks = 0; ks < 2; ++ks) {
        f16x8 afrag = *(const f16x8*)&zT[(16 * wv + m) * ZSTR + 32 * ks + 8 * q];
#pragma unroll
        for (int c = 0; c < 3; ++c)
            acc2[c] = __builtin_amdgcn_mfma_f32_16x16x32_f16(afrag, w2f8[(ks * 3 + c) * 64 + L], acc2[c], 0, 0, 0);
    }
#pragma unroll
    for (int r = 0; r < 4; ++r) {
        int node = nodeBase + 16 * wv + q * 4 + r;
        if (node < N_NODES) {
            float di = dinv[node];
            h2p[(size_t)node * OUT_DIM + m]      = (f16)(acc2[0][r] * di);
            h2p[(size_t)node * OUT_DIM + 16 + m] = (f16)(acc2[1][r] * di);
            if (m < 8)
                h2p[(size_t)node * OUT_DIM + 32 + m] = (f16)(acc2[2][r] * di);
        }
    }
}

// agg2: 1 node per 8-lane group (lanes s<5 carry the 80B row as f16x8),
// 32 groups per block; unroll-4 with masked tail -> 32 rows in flight per wave.
__global__ __launch_bounds__(256) void agg2_kernel(const f16* __restrict__ h2p,
                                                   const int* __restrict__ csr,
                                                   const int* __restrict__ row_start,
                                                   const int* __restrict__ cnt,
                                                   const float* __restrict__ dinv,
                                                   const float* __restrict__ b2,
                                                   float* __restrict__ out) {
    int t = threadIdx.x;
    int node = blockIdx.x * 32 + (t >> 3);
    int s = t & 7;                        // f16x8 slot: dims 8s..8s+7 (active s<5)
    if (node >= N_NODES || s >= 5) return;
    const f16x8* h8 = (const f16x8*)h2p;  // row stride 5 (f16x8 units)
    float acc[8];
    {
        f16x8 sv = h8[(size_t)node * 5 + s];   // self loop
#pragma unroll
        for (int j = 0; j < 8; ++j) acc[j] = (float)sv[j];
    }
    int lim = cnt[node];
    const int* cp = csr + row_start[node];
    for (int k = 0; k < lim; k += 4) {
        int k1 = (k + 1 < lim) ? k + 1 : k;
        int k2 = (k + 2 < lim) ? k + 2 : k;
        int k3 = (k + 3 < lim) ? k + 3 : k;
        int i0 = cp[k], i1 = cp[k1], i2 = cp[k2], i3 = cp[k3];
        f16x8 f0 = h8[(size_t)i0 * 5 + s];
        f16x8 f1 = h8[(size_t)i1 * 5 + s];
        f16x8 f2 = h8[(size_t)i2 * 5 + s];
        f16x8 f3 = h8[(size_t)i3 * 5 + s];
        float m1 = (k + 1 < lim) ? 1.f : 0.f;
        float m2 = (k + 2 < lim) ? 1.f : 0.f;
        float m3 = (k + 3 < lim) ? 1.f : 0.f;
#pragma unroll
        for (int j = 0; j < 8; ++j)
            acc[j] += (float)f0[j] + m1 * (float)f1[j] + m2 * (float)f2[j] + m3 * (float)f3[j];
    }
    float di = dinv[node];
    float4 o0, o1;
    o0.x = acc[0] * di + b2[8 * s + 0];
    o0.y = acc[1] * di + b2[8 * s + 1];
    o0.z = acc[2] * di + b2[8 * s + 2];
    o0.w = acc[3] * di + b2[8 * s + 3];
    o1.x = acc[4] * di + b2[8 * s + 4];
    o1.y = acc[5] * di + b2[8 * s + 5];
    o1.z = acc[6] * di + b2[8 * s + 6];
    o1.w = acc[7] * di + b2[8 * s + 7];
    *(float4*)&out[(size_t)node * OUT_DIM + 8 * s] = o0;
    *(float4*)&out[(size_t)node * OUT_DIM + 8 * s + 4] = o1;
}

extern "C" void kernel_launch(void* const* d_in, const int* in_sizes, int n_in,
                              void* d_out, int out_size, void* d_ws, size_t ws_size,
                              hipStream_t stream) {
    const float* x  = (const float*)d_in[0];
    const int*   ei = (const int*)d_in[1];      // [2, E] int32
    const float* W1 = (const float*)d_in[2];
    const float* b1 = (const float*)d_in[3];
    const float* W2 = (const float*)d_in[4];
    const float* b2 = (const float*)d_in[5];
    float* out = (float*)d_out;

    const int* src = ei;
    const int* dst = ei + N_EDGES;

    int* wsi        = (int*)d_ws;
    int* hist       = wsi;
    int* base       = hist + N_CHUNKS * N_BUCKETS;
    int* bucketTotal= base + N_BUCKETS * N_CHUNKS;
    int* bucketBase = bucketTotal + 1024;
    int* row_start  = bucketBase + 1024;
    int* cnt        = row_start + NPAD;
    int* csr        = cnt + NPAD;
    int* stage      = csr + N_EDGES;
    float* dinv     = (float*)(stage + N_EDGES);
    f16*   h1p      = (f16*)(dinv + NPAD);
    f16*   h2p      = h1p + (size_t)N_NODES * HID_DIM;
    f16*   w1f      = h2p + (size_t)N_NODES * OUT_DIM;   // 8192 f16
    f16*   w2f      = w1f + 8192;                        // 3072 f16

    hist_kernel<<<N_CHUNKS, 256, 0, stream>>>(dst, hist);
    scan_chunks_kernel<<<N_BUCKETS, 256, 0, stream>>>(hist, base, bucketTotal);
    scan_buckets_kernel<<<1, 256, 0, stream>>>(bucketTotal, bucketBase);
    scatter_kernel<<<N_CHUNKS, 256, 0, stream>>>(src, dst, base, bucketBase, stage);
    place_kernel<<<N_BUCKETS, 256, 0, stream>>>(stage, bucketBase, csr, row_start, cnt, dinv);

    wfrag_kernel<<<6, 256, 0, stream>>>(W1, W2, w1f, w2f);
    gemm1_kernel<<<(N_NODES + 63) / 64, 256, 0, stream>>>(x, w1f, dinv, h1p);
    agg1mm_kernel<<<(N_NODES + 63) / 64, 256, 0, stream>>>(h1p, csr, row_start, cnt, dinv, b1, w2f, h2p);
    agg2_kernel<<<(N_NODES + 31) / 32, 256, 0, stream>>>(h2p, csr, row_start, cnt, dinv, b2, out);
}